// Round 1
// baseline (117.978 us; speedup 1.0000x reference)
//
#include <hip/hip_runtime.h>
#include <hip/hip_bf16.h>

// Problem constants (fixed by setup_inputs): x [2,4,256,256] f32, y_ [2,1,256,256] i32
#define B_ 2
#define C_ 4
#define H_ 256
#define W_ 256
constexpr int BC   = B_ * C_;
constexpr int HW   = H_ * W_;
constexpr int NTOT = B_ * C_ * HW;              // 524288
constexpr float BIG = (float)(H_ + W_);         // matches reference init

// ---------------------------------------------------------------------------
// Kernel 1: vertical EDT pass. One block per (b,c) image, thread w = column.
// Forward + backward run-length scans over H, g = min of the two.
// Also zero-initializes the control area (maxd2[BC] + accum[1]) — ws is
// poisoned to 0xAA before every timed launch.
// ---------------------------------------------------------------------------
__global__ void edt_vertical(const int* __restrict__ lab, float* __restrict__ g,
                             float* __restrict__ ctrl) {
    const int bc = blockIdx.x;
    const int b = bc / C_, c = bc % C_;
    const int w = threadIdx.x;
    const int* lp = lab + b * HW;
    float* gp = g + bc * HW;

    float d = BIG;
    for (int h = 0; h < H_; ++h) {
        d = (lp[h * W_ + w] != c) ? 0.0f : d + 1.0f;
        gp[h * W_ + w] = d;
    }
    d = BIG;
    for (int h = H_ - 1; h >= 0; --h) {
        d = (lp[h * W_ + w] != c) ? 0.0f : d + 1.0f;
        float v = gp[h * W_ + w];
        gp[h * W_ + w] = v < d ? v : d;
    }
    if (bc == 0 && w < BC + 1) ctrl[w] = 0.0f;   // maxd2 bits (0u == 0.0f) + accum
}

// ---------------------------------------------------------------------------
// Kernel 2: horizontal pass. One block per row (B*C*H rows), thread j = pixel.
// d2[j] = min_{j'} g[j']^2 + (j-j')^2, searched outward bounded by current
// best (any dj with dj^2 >= best cannot improve). In-place overwrite of g
// with d2. Block max -> atomicMax on uint bits (valid for floats >= 0).
// ---------------------------------------------------------------------------
__global__ void edt_horiz(float* __restrict__ g, unsigned int* __restrict__ maxd2bits) {
    const int row = blockIdx.x;          // 0 .. BC*H-1
    const int bc  = row / H_;
    const int j   = threadIdx.x;
    float* grow = g + row * W_;

    __shared__ float g2[W_];
    const float gj = grow[j];
    g2[j] = gj * gj;
    __syncthreads();

    float best = gj * gj;
    if (best > 0.0f) {
        for (int dj = 1; dj < W_ && (float)(dj * dj) < best; ++dj) {
            const float dd = (float)(dj * dj);
            const int l = j - dj, r = j + dj;
            if (l >= 0) { float v = g2[l] + dd; best = v < best ? v : best; }
            if (r < W_) { float v = g2[r] + dd; best = v < best ? v : best; }
        }
    }
    grow[j] = best;                      // now holds d2

    // block-wide max reduction
    float m = best;
    #pragma unroll
    for (int off = 32; off; off >>= 1) m = fmaxf(m, __shfl_down(m, off, 64));
    __shared__ float wmax[4];
    const int lane = threadIdx.x & 63, wid = threadIdx.x >> 6;
    if (lane == 0) wmax[wid] = m;
    __syncthreads();
    if (threadIdx.x == 0) {
        float mm = fmaxf(fmaxf(wmax[0], wmax[1]), fmaxf(wmax[2], wmax[3]));
        atomicMax(&maxd2bits[bc], __float_as_uint(mm));
    }
}

// ---------------------------------------------------------------------------
// Kernel 3: softmax over C + rrw + global mean accumulation.
// One thread per (b,h,w) pixel; block reduce; one atomicAdd per block.
// rrw = 1.0 where d2 == 0 (matches reference: -(0/maxd) == -0.0 == 0.0 -> 1.0),
// else -(sqrt(d2) / (sqrt(maxd2) + 1e-15)).
// ---------------------------------------------------------------------------
__global__ void finalize_sum(const float* __restrict__ x, const float* __restrict__ d2,
                             const unsigned int* __restrict__ maxd2bits,
                             float* __restrict__ accum) {
    const int idx = blockIdx.x * blockDim.x + threadIdx.x;   // 0 .. B*HW-1
    const int b  = idx / HW;
    const int hw = idx - b * HW;
    const int base = b * C_ * HW + hw;

    float xs[C_];
    float mx = -1e30f;
    #pragma unroll
    for (int c = 0; c < C_; ++c) { xs[c] = x[base + c * HW]; mx = fmaxf(mx, xs[c]); }
    float s = 0.0f;
    #pragma unroll
    for (int c = 0; c < C_; ++c) { xs[c] = __expf(xs[c] - mx); s += xs[c]; }
    const float inv = 1.0f / s;

    float acc = 0.0f;
    #pragma unroll
    for (int c = 0; c < C_; ++c) {
        const float dd = d2[base + c * HW];
        const float maxd = sqrtf(__uint_as_float(maxd2bits[b * C_ + c]));
        const float rrw = (dd == 0.0f) ? 1.0f : -(sqrtf(dd) / (maxd + 1e-15f));
        acc += xs[c] * inv * rrw;
    }

    // block-wide sum reduction
    float v = acc;
    #pragma unroll
    for (int off = 32; off; off >>= 1) v += __shfl_down(v, off, 64);
    __shared__ float wsum[4];
    const int lane = threadIdx.x & 63, wid = threadIdx.x >> 6;
    if (lane == 0) wsum[wid] = v;
    __syncthreads();
    if (threadIdx.x == 0)
        atomicAdd(accum, wsum[0] + wsum[1] + wsum[2] + wsum[3]);
}

// ---------------------------------------------------------------------------
// Kernel 4: scalar epilogue. Division by pow-2 count is exact.
// ---------------------------------------------------------------------------
__global__ void write_out(const float* __restrict__ accum, float* __restrict__ out) {
    out[0] = accum[0] / (float)NTOT;
}

extern "C" void kernel_launch(void* const* d_in, const int* in_sizes, int n_in,
                              void* d_out, int out_size, void* d_ws, size_t ws_size,
                              hipStream_t stream) {
    const float* x   = (const float*)d_in[0];   // [B,C,H,W] f32
    const int*   y   = (const int*)d_in[1];     // [B,1,H,W] i32
    float* out = (float*)d_out;

    // ws layout: [0, NTOT) g/d2 buffer | [NTOT, NTOT+BC) maxd2 bits | [NTOT+BC] accum
    float* g = (float*)d_ws;
    float* ctrl = g + NTOT;
    unsigned int* maxbits = (unsigned int*)ctrl;
    float* accum = ctrl + BC;

    edt_vertical<<<BC, W_, 0, stream>>>(y, g, ctrl);
    edt_horiz<<<BC * H_, W_, 0, stream>>>(g, maxbits);
    finalize_sum<<<(B_ * HW) / 256, 256, 0, stream>>>(x, g, maxbits, accum);
    write_out<<<1, 1, 0, stream>>>(accum, out);
}

// Round 2
// 66.603 us; speedup vs baseline: 1.7713x; 1.7713x over previous
//
#include <hip/hip_runtime.h>

// Problem constants (fixed by setup_inputs): x [2,4,256,256] f32, y_ [2,1,256,256] i32
#define B_ 2
#define C_ 4
#define H_ 256
#define W_ 256
constexpr int BC    = B_ * C_;
constexpr int HW    = H_ * W_;
constexpr int NROWS = BC * H_;                 // 2048
constexpr int NTOT  = B_ * C_ * HW;            // 524288
constexpr float BIGF = (float)(H_ + W_);       // matches reference scan init

// ---------------------------------------------------------------------------
// Kernel A: one block per (b,c,i) row; thread j = pixel.
//  1. vertical nearest-(label!=c) search, on the fly, exact reference
//     semantics: up = i-i' for nearest i'<=i with lab!=c, else BIG+i+1;
//     down likewise, else BIG+(H-i). g = min(up,down).
//  2. bounded horizontal pass over LDS g^2: d2 = min_j' g[j']^2+(j-j')^2.
//  3. fused softmax over C=4 at (b,i,j); per-row partials:
//     pa = sum p*[d2==0], ps = sum p*sqrt(d2) [d2!=0], pm = max d2.
// No atomics, no ws pre-init dependency (partials written unconditionally).
// ---------------------------------------------------------------------------
__global__ __launch_bounds__(256) void rows_kernel(
    const int* __restrict__ lab, const float* __restrict__ x,
    float* __restrict__ pa, float* __restrict__ ps, float* __restrict__ pm) {
    const int r  = blockIdx.x;        // 0 .. NROWS-1
    const int bc = r >> 8;            // / H_
    const int i  = r & (H_ - 1);
    const int b  = bc >> 2;           // / C_
    const int c  = bc & (C_ - 1);
    const int j  = threadIdx.x;
    const int* lcol = lab + b * HW + j;      // column j, stride W_

    // --- vertical search (coalesced across j; expected ~1.3 steps/dir) ---
    float up;
    {
        int k = 0;
        for (;;) {
            const int row = i - k;
            if (row < 0) { up = BIGF + (float)(i + 1); break; }
            if (lcol[row * W_] != c) { up = (float)k; break; }
            ++k;
        }
    }
    float dn;
    {
        int k = 0;
        for (;;) {
            const int row = i + k;
            if (row >= H_) { dn = BIGF + (float)(H_ - i); break; }
            if (lcol[row * W_] != c) { dn = (float)k; break; }
            ++k;
        }
    }
    const float g = fminf(up, dn);

    // --- horizontal bounded min over g^2 in LDS ---
    __shared__ float g2s[W_];
    const float g2 = g * g;
    g2s[j] = g2;
    __syncthreads();

    float best = g2;
    if (best > 0.0f) {
        for (int dj = 1; dj < W_; ++dj) {
            const float dd = (float)(dj * dj);
            if (dd >= best) break;
            const int l = j - dj, rr = j + dj;
            if (l >= 0)  best = fminf(best, g2s[l] + dd);
            if (rr < W_) best = fminf(best, g2s[rr] + dd);
        }
    }
    // best == d2 at (b,c,i,j)

    // --- softmax over channels at (b,i,j) ---
    const float* xp = x + b * C_ * HW + i * W_ + j;
    const float x0 = xp[0 * HW], x1 = xp[1 * HW], x2 = xp[2 * HW], x3 = xp[3 * HW];
    const float mx = fmaxf(fmaxf(x0, x1), fmaxf(x2, x3));
    const float e0 = __expf(x0 - mx), e1 = __expf(x1 - mx);
    const float e2 = __expf(x2 - mx), e3 = __expf(x3 - mx);
    const float ec = (c == 0) ? e0 : (c == 1) ? e1 : (c == 2) ? e2 : e3;
    const float p  = ec / (e0 + e1 + e2 + e3);

    float va = (best == 0.0f) ? p : 0.0f;            // contributes rrw=+1
    float vs = (best == 0.0f) ? 0.0f : p * sqrtf(best); // scaled by -1/maxd later
    float vm = best;

    // --- block reduce: sum(va), sum(vs), max(vm) ---
    #pragma unroll
    for (int off = 32; off; off >>= 1) {
        va += __shfl_down(va, off, 64);
        vs += __shfl_down(vs, off, 64);
        vm = fmaxf(vm, __shfl_down(vm, off, 64));
    }
    __shared__ float sa[4], ss[4], sm[4];
    const int lane = j & 63, wid = j >> 6;
    if (lane == 0) { sa[wid] = va; ss[wid] = vs; sm[wid] = vm; }
    __syncthreads();
    if (j == 0) {
        pa[r] = sa[0] + sa[1] + sa[2] + sa[3];
        ps[r] = ss[0] + ss[1] + ss[2] + ss[3];
        pm[r] = fmaxf(fmaxf(sm[0], sm[1]), fmaxf(sm[2], sm[3]));
    }
}

// ---------------------------------------------------------------------------
// Kernel B: single block; reduce 2048-row partials per (b,c), combine:
//   total = sum_bc ( A_bc - S_bc / (sqrt(maxd2_bc) + 1e-15) );  out = total/N
// ---------------------------------------------------------------------------
__global__ __launch_bounds__(256) void final_kernel(
    const float* __restrict__ pa, const float* __restrict__ ps,
    const float* __restrict__ pm, float* __restrict__ out) {
    const int t = threadIdx.x;
    __shared__ float sa[4], ss[4], sm[4];
    float total = 0.0f;                      // accumulated by thread 0
    for (int bc = 0; bc < BC; ++bc) {
        const int r = bc * H_ + t;
        float va = pa[r], vs = ps[r], vm = pm[r];
        #pragma unroll
        for (int off = 32; off; off >>= 1) {
            va += __shfl_down(va, off, 64);
            vs += __shfl_down(vs, off, 64);
            vm = fmaxf(vm, __shfl_down(vm, off, 64));
        }
        const int lane = t & 63, wid = t >> 6;
        __syncthreads();                     // protect scratch from prior iter
        if (lane == 0) { sa[wid] = va; ss[wid] = vs; sm[wid] = vm; }
        __syncthreads();
        if (t == 0) {
            const float A = sa[0] + sa[1] + sa[2] + sa[3];
            const float S = ss[0] + ss[1] + ss[2] + ss[3];
            const float M = fmaxf(fmaxf(sm[0], sm[1]), fmaxf(sm[2], sm[3]));
            total += A - S / (sqrtf(M) + 1e-15f);
        }
    }
    if (t == 0) out[0] = total / (float)NTOT;
}

extern "C" void kernel_launch(void* const* d_in, const int* in_sizes, int n_in,
                              void* d_out, int out_size, void* d_ws, size_t ws_size,
                              hipStream_t stream) {
    const float* x = (const float*)d_in[0];   // [B,C,H,W] f32
    const int*   y = (const int*)d_in[1];     // [B,1,H,W] i32
    float* out = (float*)d_out;

    // ws layout: pa[NROWS] | ps[NROWS] | pm[NROWS]  (24 KB total)
    float* pa = (float*)d_ws;
    float* ps = pa + NROWS;
    float* pm = ps + NROWS;

    rows_kernel<<<NROWS, W_, 0, stream>>>(y, x, pa, ps, pm);
    final_kernel<<<1, 256, 0, stream>>>(pa, ps, pm, out);
}

// Round 3
// 63.858 us; speedup vs baseline: 1.8475x; 1.0430x over previous
//
#include <hip/hip_runtime.h>

// Problem constants (fixed by setup_inputs): x [2,4,256,256] f32, y_ [2,1,256,256] i32
#define B_ 2
#define C_ 4
#define H_ 256
#define W_ 256
constexpr int BC    = B_ * C_;
constexpr int HW    = H_ * W_;
constexpr int NROWS = B_ * H_;                 // 512 (one per (b,i) row now)
constexpr int NTOT  = B_ * C_ * HW;            // 524288
constexpr float BIGF = (float)(H_ + W_);       // matches reference scan init

// ---------------------------------------------------------------------------
// Kernel A: one block per (b,i) image row; thread j = pixel.
// Key fact: for the one-hot EDT, pixel (i,j) has d=0 for every channel except
// its own label c* (the pixel itself is a zero-pixel for all c != c*). So:
//   - channels c != c*: rrw = 1, contribute sum_{c!=c*} p_c = 1 - p_{c*}
//   - channel c*: d2 >= 1, contributes p_{c*} * (-sqrt(d2)/(maxd_{c*}+eps))
// Per pixel we therefore need ONE vertical search (own channel) and one
// softmax. Horizontal pass: g_{c*}[j'] = (lab[j']==c*) ? own_g[j'] : 0.
// Per-row partials: A (scalar), S[c] = sum p*sqrt(d2), M[c] = max d2.
// ---------------------------------------------------------------------------
__global__ __launch_bounds__(256) void rows_kernel(
    const int* __restrict__ lab, const float* __restrict__ x,
    float* __restrict__ ps4, float* __restrict__ pm4, float* __restrict__ pa) {
    const int r = blockIdx.x;         // 0 .. NROWS-1  (= b*H + i)
    const int b = r >> 8;
    const int i = r & (H_ - 1);
    const int j = threadIdx.x;

    const int* lrow = lab + b * HW + i * W_;
    const int  c    = lrow[j];                 // own label c*

    // x loads early (independent of everything below)
    const float* xp = x + b * C_ * HW + i * W_ + j;
    const float x0 = xp[0 * HW], x1 = xp[1 * HW], x2 = xp[2 * HW], x3 = xp[3 * HW];

    // --- vertical search for own channel: nearest row with lab != c.
    // up/down chains merged so their load latencies overlap. Reference
    // defaults: no hit above -> BIG+(i+1); no hit below -> BIG+(H-i).
    const int* lcol = lab + b * HW + j;
    float gu = -1.0f, gd = -1.0f;
    for (int k = 1; gu < 0.0f || gd < 0.0f; ++k) {
        if (gu < 0.0f) {
            const int rr = i - k;
            if (rr < 0) gu = BIGF + (float)(i + 1);
            else if (lcol[rr * W_] != c) gu = (float)k;
        }
        if (gd < 0.0f) {
            const int rr = i + k;
            if (rr >= H_) gd = BIGF + (float)(H_ - i);
            else if (lcol[rr * W_] != c) gd = (float)k;
        }
    }
    const float g = fminf(gu, gd);

    // --- horizontal bounded min over per-channel g^2 in LDS ---
    __shared__ int   ls[W_];
    __shared__ float g2s[W_];
    ls[j]  = c;
    g2s[j] = g * g;
    __syncthreads();

    float best = g * g;                        // own-channel d2, >= 1 always
    for (int dj = 1; dj < W_; ++dj) {
        const float dd = (float)(dj * dj);
        if (dd >= best) break;
        const int l = j - dj, rr = j + dj;
        if (l >= 0) {
            const float v = (ls[l] == c ? g2s[l] : 0.0f) + dd;
            best = fminf(best, v);
        }
        if (rr < W_) {
            const float v = (ls[rr] == c ? g2s[rr] : 0.0f) + dd;
            best = fminf(best, v);
        }
    }

    // --- softmax over C=4 at (b,i,j) ---
    const float mx = fmaxf(fmaxf(x0, x1), fmaxf(x2, x3));
    const float e0 = __expf(x0 - mx), e1 = __expf(x1 - mx);
    const float e2 = __expf(x2 - mx), e3 = __expf(x3 - mx);
    const float s  = e0 + e1 + e2 + e3;
    const float ec = (c == 0) ? e0 : (c == 1) ? e1 : (c == 2) ? e2 : e3;
    const float pc = ec / s;

    float va = (s - ec) / s;                   // = sum_{c' != c} p_{c'}, rrw=+1
    const float psv = pc * sqrtf(best);        // scaled by -1/maxd_c later
    float s0 = (c == 0) ? psv : 0.0f, s1 = (c == 1) ? psv : 0.0f;
    float s2 = (c == 2) ? psv : 0.0f, s3 = (c == 3) ? psv : 0.0f;
    float m0 = (c == 0) ? best : 0.0f, m1 = (c == 1) ? best : 0.0f;
    float m2 = (c == 2) ? best : 0.0f, m3 = (c == 3) ? best : 0.0f;

    // --- block reduce: 1 sum + 4 channel sums + 4 channel maxes ---
    #pragma unroll
    for (int off = 32; off; off >>= 1) {
        va += __shfl_down(va, off, 64);
        s0 += __shfl_down(s0, off, 64);
        s1 += __shfl_down(s1, off, 64);
        s2 += __shfl_down(s2, off, 64);
        s3 += __shfl_down(s3, off, 64);
        m0 = fmaxf(m0, __shfl_down(m0, off, 64));
        m1 = fmaxf(m1, __shfl_down(m1, off, 64));
        m2 = fmaxf(m2, __shfl_down(m2, off, 64));
        m3 = fmaxf(m3, __shfl_down(m3, off, 64));
    }
    __shared__ float lred[4][9];
    const int lane = j & 63, wid = j >> 6;
    if (lane == 0) {
        lred[wid][0] = va;
        lred[wid][1] = s0; lred[wid][2] = s1; lred[wid][3] = s2; lred[wid][4] = s3;
        lred[wid][5] = m0; lred[wid][6] = m1; lred[wid][7] = m2; lred[wid][8] = m3;
    }
    __syncthreads();
    if (j == 0) {
        float A = 0.0f, S0 = 0.0f, S1 = 0.0f, S2 = 0.0f, S3 = 0.0f;
        float M0 = 0.0f, M1 = 0.0f, M2 = 0.0f, M3 = 0.0f;
        #pragma unroll
        for (int w = 0; w < 4; ++w) {
            A  += lred[w][0];
            S0 += lred[w][1]; S1 += lred[w][2]; S2 += lred[w][3]; S3 += lred[w][4];
            M0 = fmaxf(M0, lred[w][5]); M1 = fmaxf(M1, lred[w][6]);
            M2 = fmaxf(M2, lred[w][7]); M3 = fmaxf(M3, lred[w][8]);
        }
        ((float4*)ps4)[r] = make_float4(S0, S1, S2, S3);
        ((float4*)pm4)[r] = make_float4(M0, M1, M2, M3);
        pa[r] = A;
    }
}

// ---------------------------------------------------------------------------
// Kernel B: single block; per b reduce 256-row partials, combine:
//   total = sum_b [ A_b + sum_c ( -S_{b,c} / (sqrt(M_{b,c}) + 1e-15) ) ]
//   out = total / NTOT
// ---------------------------------------------------------------------------
__global__ __launch_bounds__(256) void final_kernel(
    const float4* __restrict__ ps4, const float4* __restrict__ pm4,
    const float* __restrict__ pa, float* __restrict__ out) {
    const int t = threadIdx.x;
    const int lane = t & 63, wid = t >> 6;
    __shared__ float lred[4][9];
    float total = 0.0f;                        // meaningful on thread 0 only
    for (int b = 0; b < B_; ++b) {
        const int r = b * H_ + t;
        float4 s4 = ps4[r];
        float4 m4 = pm4[r];
        float  a  = pa[r];
        #pragma unroll
        for (int off = 32; off; off >>= 1) {
            a    += __shfl_down(a, off, 64);
            s4.x += __shfl_down(s4.x, off, 64);
            s4.y += __shfl_down(s4.y, off, 64);
            s4.z += __shfl_down(s4.z, off, 64);
            s4.w += __shfl_down(s4.w, off, 64);
            m4.x = fmaxf(m4.x, __shfl_down(m4.x, off, 64));
            m4.y = fmaxf(m4.y, __shfl_down(m4.y, off, 64));
            m4.z = fmaxf(m4.z, __shfl_down(m4.z, off, 64));
            m4.w = fmaxf(m4.w, __shfl_down(m4.w, off, 64));
        }
        __syncthreads();                       // protect LDS from prior iter
        if (lane == 0) {
            lred[wid][0] = a;
            lred[wid][1] = s4.x; lred[wid][2] = s4.y;
            lred[wid][3] = s4.z; lred[wid][4] = s4.w;
            lred[wid][5] = m4.x; lred[wid][6] = m4.y;
            lred[wid][7] = m4.z; lred[wid][8] = m4.w;
        }
        __syncthreads();
        if (t == 0) {
            float A = 0.0f, S0 = 0.0f, S1 = 0.0f, S2 = 0.0f, S3 = 0.0f;
            float M0 = 0.0f, M1 = 0.0f, M2 = 0.0f, M3 = 0.0f;
            #pragma unroll
            for (int w = 0; w < 4; ++w) {
                A  += lred[w][0];
                S0 += lred[w][1]; S1 += lred[w][2]; S2 += lred[w][3]; S3 += lred[w][4];
                M0 = fmaxf(M0, lred[w][5]); M1 = fmaxf(M1, lred[w][6]);
                M2 = fmaxf(M2, lred[w][7]); M3 = fmaxf(M3, lred[w][8]);
            }
            total += A - S0 / (sqrtf(M0) + 1e-15f) - S1 / (sqrtf(M1) + 1e-15f)
                       - S2 / (sqrtf(M2) + 1e-15f) - S3 / (sqrtf(M3) + 1e-15f);
        }
    }
    if (t == 0) out[0] = total / (float)NTOT;
}

extern "C" void kernel_launch(void* const* d_in, const int* in_sizes, int n_in,
                              void* d_out, int out_size, void* d_ws, size_t ws_size,
                              hipStream_t stream) {
    const float* x = (const float*)d_in[0];   // [B,C,H,W] f32
    const int*   y = (const int*)d_in[1];     // [B,1,H,W] i32
    float* out = (float*)d_out;

    // ws layout (16B-aligned): ps4[512*4] | pm4[512*4] | pa[512]
    float* ps4 = (float*)d_ws;
    float* pm4 = ps4 + NROWS * 4;
    float* pa  = pm4 + NROWS * 4;

    rows_kernel<<<NROWS, W_, 0, stream>>>(y, x, ps4, pm4, pa);
    final_kernel<<<1, 256, 0, stream>>>((const float4*)ps4, (const float4*)pm4, pa, out);
}